// Round 3
// baseline (440.456 us; speedup 1.0000x reference)
//
#include <hip/hip_runtime.h>

#define DEV_INLINE __device__ __forceinline__

typedef float nfloat4 __attribute__((ext_vector_type(4)));  // native vec for nontemporal builtins

// Problem constants (B,L,E,H,HD) = (2,256,512,8,64)
static constexpr int Bb = 2, Ls = 256, E = 512, H = 8;
static constexpr int BL = Bb * Ls;  // 512

// workspace layout in floats
static constexpr size_t WS_QP = 0;
static constexpr size_t WS_KP = WS_QP + (size_t)BL * E;       // 262144
static constexpr size_t WS_VP = WS_KP + (size_t)BL * E;
static constexpr size_t WS_M  = WS_VP + (size_t)BL * E;       // BL*H*E = 2097152
static constexpr size_t WS_C  = WS_M  + (size_t)BL * H * E;   // 4096, layout [b][h][k]
static constexpr size_t WS_O  = WS_C  + (size_t)BL * H;       // 262144
static constexpr size_t WS_QK = WS_O  + (size_t)BL * E;       // B*H*L*L = 1048576
// total ~4.2M floats = 17 MB (ws is 1 GiB; poison cost is harness-fixed)

DEV_INLINE float dot4n(nfloat4 a, float4 b) {
  return a.x * b.x + a.y * b.y + a.z * b.z + a.w * b.w;
}

// ---------------- generic tiled fp32 GEMM core ----------------
// Tile is (16*RPT) rows x 64 cols, 256 threads, RPT outputs-rows/thread.
// Register double-buffered staging: next k-step's global loads are issued
// right after the first barrier so their latency hides under the FMA block —
// critical for the ~1-block/CU launches where no other wavefronts cover the
// barrier-exposed load latency.
template <int TRANSB, int RPT>
DEV_INLINE void gemm_tile(const float* __restrict__ A, int lda,
                          const float* __restrict__ B, int ldb,
                          float* __restrict__ C, int ldc, int Ksz,
                          const float* __restrict__ bias, int i0, int j0) {
  constexpr int TM = 16 * RPT;
  __shared__ float As[16][TM + 4];
  __shared__ float Bs[16][68];
  const int t = threadIdx.x;
  const int tx = t & 15, ty = t >> 4;
  const int ar = t >> 2, ac = t & 3;  // staging: row 0..TM-1, k-chunk 0..3
  const bool aload = (t < 64 * RPT);
  float acc[RPT][4] = {};

  float4 av, bv;
  if (aload) av = *(const float4*)&A[(size_t)(i0 + ar) * lda + 4 * ac];
  if (TRANSB == 0)
    bv = *(const float4*)&B[(size_t)ty * ldb + (j0 + 4 * tx)];
  else
    bv = *(const float4*)&B[(size_t)(j0 + ar) * ldb + 4 * ac];

  for (int k0 = 0; k0 < Ksz; k0 += 16) {
    if (aload) {
      As[4 * ac + 0][ar] = av.x;
      As[4 * ac + 1][ar] = av.y;
      As[4 * ac + 2][ar] = av.z;
      As[4 * ac + 3][ar] = av.w;
    }
    if (TRANSB == 0) {
      *(float4*)&Bs[ty][4 * tx] = bv;
    } else {
      Bs[4 * ac + 0][ar] = bv.x;
      Bs[4 * ac + 1][ar] = bv.y;
      Bs[4 * ac + 2][ar] = bv.z;
      Bs[4 * ac + 3][ar] = bv.w;
    }
    __syncthreads();
    const int k1 = k0 + 16;
    if (k1 < Ksz) {  // prefetch next tile into registers during compute
      if (aload) av = *(const float4*)&A[(size_t)(i0 + ar) * lda + (k1 + 4 * ac)];
      if (TRANSB == 0)
        bv = *(const float4*)&B[(size_t)(k1 + ty) * ldb + (j0 + 4 * tx)];
      else
        bv = *(const float4*)&B[(size_t)(j0 + ar) * ldb + (k1 + 4 * ac)];
    }
#pragma unroll
    for (int kk = 0; kk < 16; ++kk) {
      float a[RPT];
      if constexpr (RPT == 4) {
        float4 a4 = *(const float4*)&As[kk][ty * 4];
        a[0] = a4.x; a[1] = a4.y; a[2] = a4.z; a[3] = a4.w;
      } else if constexpr (RPT == 2) {
        float2 a2 = *(const float2*)&As[kk][ty * 2];
        a[0] = a2.x; a[1] = a2.y;
      } else {
        a[0] = As[kk][ty];
      }
      float4 b4 = *(const float4*)&Bs[kk][tx * 4];
#pragma unroll
      for (int r = 0; r < RPT; ++r) {
        acc[r][0] += a[r] * b4.x;
        acc[r][1] += a[r] * b4.y;
        acc[r][2] += a[r] * b4.z;
        acc[r][3] += a[r] * b4.w;
      }
    }
    __syncthreads();
  }
#pragma unroll
  for (int r = 0; r < RPT; ++r) {
#pragma unroll
    for (int c2 = 0; c2 < 4; ++c2) {
      float v = acc[r][c2];
      if (bias) v += bias[j0 + tx * 4 + c2];
      C[(size_t)(i0 + ty * RPT + r) * ldc + (j0 + tx * 4 + c2)] = v;
    }
  }
}

// K1: qp = query@Wq, kp = key@Wk, vp = value@Wq  (bug preserved: vp uses Wq)
// 32-row tiles -> 384 blocks (1.5/CU): all CUs busy, cross-block latency cover.
__global__ __launch_bounds__(256) void k1_proj(
    const float* __restrict__ q, const float* __restrict__ k,
    const float* __restrict__ v, const float* __restrict__ Wq,
    const float* __restrict__ Wk, float* __restrict__ qp,
    float* __restrict__ kp, float* __restrict__ vp) {
  const float* A; const float* Bm; float* C;
  switch (blockIdx.z) {
    case 0:  A = q; Bm = Wq; C = qp; break;
    case 1:  A = k; Bm = Wk; C = kp; break;
    default: A = v; Bm = Wq; C = vp; break;
  }
  gemm_tile<0, 2>(A, 512, Bm, 512, C, 512, 512, nullptr,
                  blockIdx.y * 32, blockIdx.x * 64);
}

// K23 (merged): blocks 0..511 compute M[bk,h,e] = kp_h @ Wr_h (plus c[b,h,k]
// on the x==0 stripe); blocks 512..767 compute qk[b,h,q,k] = qp_h . kp_h.
// Both depend only on K1 (c is folded in K4) -> one launch, full concurrency.
__global__ __launch_bounds__(256) void k23(
    const float* __restrict__ kp, const float* __restrict__ Wr,
    const float* __restrict__ br, const float* __restrict__ qp,
    float* __restrict__ M, float* __restrict__ c, float* __restrict__ qk) {
  const int blk = blockIdx.x;
  if (blk < 512) {
    const int h = blk >> 6, rem = blk & 63;
    const int by = rem >> 3, bx = rem & 7;
    if (bx == 0 && threadIdx.x < 64) {
      const int row = by * 64 + threadIdx.x;  // bk in 0..511
      float s = 0.f;
      const float* kr = kp + (size_t)row * 512 + h * 64;
      const float* bb = br + h * 64;
#pragma unroll 8
      for (int d = 0; d < 64; ++d) s += bb[d] * kr[d];
      c[((size_t)(row >> 8) * 8 + h) * 256 + (row & 255)] = s;
    }
    gemm_tile<0, 4>(kp + h * 64, 512, Wr + (size_t)h * 64 * 512, 512,
                    M + (size_t)h * 512, 4096, 64, nullptr, by * 64, bx * 64);
  } else {
    const int idx = blk - 512;
    const int z = idx >> 4;                    // b*8 + h
    const int by = (idx >> 2) & 3, bx = idx & 3;
    const int b = z >> 3, h = z & 7;
    gemm_tile<1, 4>(qp + (size_t)b * 256 * 512 + h * 64, 512,
                    kp + (size_t)b * 256 * 512 + h * 64, 512,
                    qk + (size_t)z * 65536, 256, 64, nullptr, by * 64, bx * 64);
  }
}

// K4 (hot): for block (b,k,qquarter):
//   logits[b,q,k,h] = sum_e rel[b,q,k,e]*M[b,k,h,e] + qk[b,h,q,k] + c[b,h,k]
// M now staged in LDS (16 KB) instead of 64 VGPRs/lane: VGPR ~50 ->
// __launch_bounds__(256,8) gives 8 waves/SIMD = 8 blocks/CU -> all 2048
// blocks resident in ONE batch (was 1.6 batches at the ~5 waves/SIMD VGPR
// cap). M reads are 1KB-contiguous per wave (2-way bank aliasing = free);
// aggregate LDS demand 536 MB ~ 6.8 us of the 69 TB/s pipe vs the 43 us HBM
// floor -> stays memory-bound. rel software-pipelined one q-row ahead.
__global__ __launch_bounds__(256, 8) void k4_rel(
    const float* __restrict__ rel, const float* __restrict__ Mw,
    const float* __restrict__ qk, const float* __restrict__ cbias,
    float* __restrict__ logits) {
  __shared__ float Mlds[8 * 512];
  const int blk = blockIdx.x;       // 2048
  const int bk = blk >> 2;          // 0..511
  const int qq = blk & 3;
  const int b = bk >> 8, k = bk & 255;
  const int t = threadIdx.x, w = t >> 6, lane = t & 63;

  {  // stage M panel (L2-hot, shared by the 4 qq-blocks of this bk)
    const float4* Msrc = (const float4*)(Mw + (size_t)bk * 8 * 512);
    float4* Mdst = (float4*)Mlds;
#pragma unroll
    for (int r = 0; r < 4; ++r) Mdst[t + 256 * r] = Msrc[t + 256 * r];
  }

  // writer lane h mapping (bit-reversed 3-bit)
  const int hw = ((lane & 1) << 2) | (lane & 2) | ((lane >> 2) & 1);
  const bool writer = (lane < 8);
  const float cv = writer ? cbias[((size_t)b * 8 + hw) * 256 + k] : 0.f;

  const int q0 = qq * 64 + w;  // this wave's first q; step 4, 16 iters
  const nfloat4* relp =
      (const nfloat4*)(rel) + (((size_t)b * 256 + q0) * 256 + k) * 128;
  const float* qkp = qk + ((size_t)(b * 8 + hw) * 256 + q0) * 256 + k;
  float* lp = logits + (((size_t)b * 256 + q0) * 256 + k) * 8 + hw;
  const size_t REL_STRIDE = (size_t)4 * 256 * 128;  // q += 4, in float4s
  const size_t QK_STRIDE = (size_t)4 * 256;
  const size_t L_STRIDE = (size_t)4 * 256 * 8;

  const bool b0 = (lane & 1) != 0;
  const bool b1 = (lane & 2) != 0;
  const bool b2 = (lane & 4) != 0;

  nfloat4 r0 = __builtin_nontemporal_load(&relp[lane]);
  nfloat4 r1 = __builtin_nontemporal_load(&relp[64 + lane]);
  __syncthreads();  // Mlds ready; first rel loads already in flight

  const float* Ml0 = Mlds + 4 * lane;
  const float* Ml1 = Mlds + 256 + 4 * lane;

  for (int i = 0; i < 16; ++i) {
    // keep the loop-invariant Mlds reads INSIDE the loop (LICM would hoist
    // 32 ds_read_b128 back into 128 VGPRs and blow the 8-wave budget)
    asm volatile("" ::: "memory");
    float qkv = 0.f;
    if (writer) qkv = *qkp;  // L2-hot scalar, issued early

    const bool more = (i < 15);
    nfloat4 nr0, nr1;
    if (more) {  // prefetch next q-row while computing current
      relp += REL_STRIDE;
      nr0 = __builtin_nontemporal_load(&relp[lane]);
      nr1 = __builtin_nontemporal_load(&relp[64 + lane]);
    }

    float acc[8];
#pragma unroll
    for (int h = 0; h < 8; ++h) {
      float4 mv0 = *(const float4*)(Ml0 + h * 512);
      float4 mv1 = *(const float4*)(Ml1 + h * 512);
      acc[h] = dot4n(r0, mv0) + dot4n(r1, mv1);
    }

    // reduce-scatter butterfly: bit0 picks h-bit2, bit1 -> h-bit1, bit2 -> h-bit0
    float s[4];
#pragma unroll
    for (int j = 0; j < 4; ++j) {
      float lo = acc[j], hi = acc[j + 4];
      float send = b0 ? lo : hi;
      float keep = b0 ? hi : lo;
      s[j] = keep + __shfl_xor(send, 1);
    }
    float u[2];
#pragma unroll
    for (int j = 0; j < 2; ++j) {
      float lo = s[j], hi = s[j + 2];
      float send = b1 ? lo : hi;
      float keep = b1 ? hi : lo;
      u[j] = keep + __shfl_xor(send, 2);
    }
    {
      float lo = u[0], hi = u[1];
      float send = b2 ? lo : hi;
      float keep = b2 ? hi : lo;
      float v = keep + __shfl_xor(send, 4);
      v += __shfl_xor(v, 8);
      v += __shfl_xor(v, 16);
      v += __shfl_xor(v, 32);
      if (writer) *lp = v + qkv + cv;
    }
    if (more) { r0 = nr0; r1 = nr1; }
    qkp += QK_STRIDE;
    lp += L_STRIDE;
  }
}

// K5: softmax over k per (b,q,h); writes normalized a in place (d_out region),
// then o[b,q,:] = sum_k a[k,h] * vp[b,k,:].
// FOUR q-rows per block: each vp float4 is loaded once and used for all four
// rows -> vp L2 traffic 134 MB -> 67 MB (the dominant cost of this kernel).
__global__ __launch_bounds__(256) void k5_softmax(float* __restrict__ logits,
                                                  const float* __restrict__ vp,
                                                  float* __restrict__ o) {
  const int pr = blockIdx.x;     // 0..127
  const int bq0 = pr * 4;
  const int b = bq0 >> 8;        // all rows in same batch (256 rows/batch)
  const int t = threadIdx.x;
  const float SCALE = 0.125f;    // 1/sqrt(64)

  __shared__ float tr[4][8][272];  // [row][h][k], stride 272 -> conflict-free
  __shared__ float mx[4][8], sm[4][8];
  __shared__ float ob[4][512];     // split-k partial combine

  float x[4][8];
#pragma unroll
  for (int r = 0; r < 4; ++r) {
    float* L = logits + (size_t)(bq0 + r) * 2048;
    float4 x0 = ((float4*)L)[t * 2];
    float4 x1 = ((float4*)L)[t * 2 + 1];
    x[r][0] = x0.x; x[r][1] = x0.y; x[r][2] = x0.z; x[r][3] = x0.w;
    x[r][4] = x1.x; x[r][5] = x1.y; x[r][6] = x1.z; x[r][7] = x1.w;
#pragma unroll
    for (int j = 0; j < 8; ++j) x[r][j] *= SCALE;
#pragma unroll
    for (int hh = 0; hh < 8; ++hh) tr[r][hh][t] = x[r][hh];
  }
  __syncthreads();
  const int g = t >> 5, j = t & 31;
#pragma unroll
  for (int r = 0; r < 4; ++r) {
    float m = -1e30f;
#pragma unroll
    for (int i = 0; i < 8; ++i) m = fmaxf(m, tr[r][g][j + 32 * i]);
#pragma unroll
    for (int off = 16; off >= 1; off >>= 1) m = fmaxf(m, __shfl_down(m, off, 32));
    if (j == 0) mx[r][g] = m;
  }
  __syncthreads();
  float p[4][8];
#pragma unroll
  for (int r = 0; r < 4; ++r)
#pragma unroll
    for (int hh = 0; hh < 8; ++hh) p[r][hh] = __expf(x[r][hh] - mx[r][hh]);
#pragma unroll
  for (int r = 0; r < 4; ++r)
#pragma unroll
    for (int hh = 0; hh < 8; ++hh) tr[r][hh][t] = p[r][hh];
  __syncthreads();
#pragma unroll
  for (int r = 0; r < 4; ++r) {
    float ss = 0.f;
#pragma unroll
    for (int i = 0; i < 8; ++i) ss += tr[r][g][j + 32 * i];
#pragma unroll
    for (int off = 16; off >= 1; off >>= 1) ss += __shfl_down(ss, off, 32);
    if (j == 0) sm[r][g] = ss;
  }
  __syncthreads();
#pragma unroll
  for (int r = 0; r < 4; ++r) {
    float inv[8];
#pragma unroll
    for (int hh = 0; hh < 8; ++hh) inv[hh] = 1.0f / sm[r][hh];
    float* L = logits + (size_t)(bq0 + r) * 2048;
    ((float4*)L)[t * 2] = make_float4(p[r][0] * inv[0], p[r][1] * inv[1],
                                      p[r][2] * inv[2], p[r][3] * inv[3]);
    ((float4*)L)[t * 2 + 1] = make_float4(p[r][4] * inv[4], p[r][5] * inv[5],
                                          p[r][6] * inv[6], p[r][7] * inv[7]);
  }

  // o accumulation: threads split into two k-halves; each handles 4 cols via
  // float4 loads (16 B/lane) shared across all 4 q-rows; LDS partial combine.
  const int g2 = t >> 7, tc = t & 127;  // k-half, col-group (cols 4tc..4tc+3)
  const int hc = tc >> 4;               // head of this col group
  const float4* V4 =
      (const float4*)(vp + (size_t)b * 256 * 512 + (size_t)g2 * 128 * 512) + tc;
  const float* tw[4];
#pragma unroll
  for (int r = 0; r < 4; ++r) tw[r] = &tr[r][hc][g2 * 128];
  float ax[4] = {}, ay[4] = {}, az[4] = {}, aw[4] = {};
#pragma unroll 8
  for (int kk = 0; kk < 128; ++kk) {
    float4 vv = V4[(size_t)kk * 128];
#pragma unroll
    for (int r = 0; r < 4; ++r) {
      const float wg = tw[r][kk];  // unnormalized p
      ax[r] += wg * vv.x; ay[r] += wg * vv.y;
      az[r] += wg * vv.z; aw[r] += wg * vv.w;
    }
  }
  if (g2) {
#pragma unroll
    for (int r = 0; r < 4; ++r) {
      ob[r][4 * tc + 0] = ax[r]; ob[r][4 * tc + 1] = ay[r];
      ob[r][4 * tc + 2] = az[r]; ob[r][4 * tc + 3] = aw[r];
    }
  }
  __syncthreads();
  if (!g2) {
#pragma unroll
    for (int r = 0; r < 4; ++r) {
      const float iv = 1.0f / sm[r][hc];
      float rx = (ax[r] + ob[r][4 * tc + 0]) * iv;
      float ry = (ay[r] + ob[r][4 * tc + 1]) * iv;
      float rz = (az[r] + ob[r][4 * tc + 2]) * iv;
      float rw = (aw[r] + ob[r][4 * tc + 3]) * iv;
      ((float4*)(o + (size_t)(bq0 + r) * 512))[tc] = make_float4(rx, ry, rz, rw);
    }
  }
}

// K6: out = o @ Wo.T + bo.  16-row tiles -> 256 blocks: all CUs busy.
__global__ __launch_bounds__(256) void k6_out(const float* __restrict__ o,
                                              const float* __restrict__ Wo,
                                              const float* __restrict__ bo,
                                              float* __restrict__ out) {
  gemm_tile<1, 1>(o, 512, Wo, 512, out, 512, 512, bo,
                  blockIdx.y * 16, blockIdx.x * 64);
}

extern "C" void kernel_launch(void* const* d_in, const int* in_sizes, int n_in,
                              void* d_out, int out_size, void* d_ws,
                              size_t ws_size, hipStream_t stream) {
  const float* query = (const float*)d_in[0];
  const float* key   = (const float*)d_in[1];
  const float* value = (const float*)d_in[2];
  const float* rel   = (const float*)d_in[3];
  const float* Wq    = (const float*)d_in[4];
  const float* Wk    = (const float*)d_in[5];
  // d_in[6] = Wv: unused (reference bug: v = value @ Wq)
  const float* Wr    = (const float*)d_in[7];
  const float* br    = (const float*)d_in[8];
  const float* Wo    = (const float*)d_in[9];
  const float* bo    = (const float*)d_in[10];

  float* out = (float*)d_out;                   // (B,L,E) = 262144 floats
  float* a   = (float*)d_out + (size_t)BL * E;  // (B,L,L,H); also logits scratch

  float* ws = (float*)d_ws;
  float* qp  = ws + WS_QP;
  float* kp  = ws + WS_KP;
  float* vp  = ws + WS_VP;
  float* M   = ws + WS_M;
  float* c   = ws + WS_C;
  float* o   = ws + WS_O;
  float* qkb = ws + WS_QK;

  // K1: projections (3 GEMMs 512x512x512), 32-row tiles
  k1_proj<<<dim3(8, 16, 3), 256, 0, stream>>>(query, key, value, Wq, Wk, qp, kp, vp);
  // K23: M per head + c bias (blocks 0..511) and qk GEMMs (blocks 512..767)
  k23<<<dim3(768), 256, 0, stream>>>(kp, Wr, br, qp, M, c, qkb);
  // K4: logits = rel.M + qk + c  (2048 blocks, single-batch residency)
  k4_rel<<<dim3(2048), 256, 0, stream>>>(rel, M, qkb, c, a);
  // K5: softmax (in-place -> a) + o = a.vp  (4 q-rows per block)
  k5_softmax<<<dim3(128), 256, 0, stream>>>(a, vp, o);
  // K6: out = o @ Wo.T + bo  (16-row tiles, 256 blocks)
  k6_out<<<dim3(8, 32, 1), 256, 0, stream>>>(o, Wo, bo, out);
}

// Round 4
// 437.506 us; speedup vs baseline: 1.0067x; 1.0067x over previous
//
#include <hip/hip_runtime.h>

#define DEV_INLINE __device__ __forceinline__

typedef float nfloat4 __attribute__((ext_vector_type(4)));  // native vec for nontemporal builtins

// Problem constants (B,L,E,H,HD) = (2,256,512,8,64)
static constexpr int Bb = 2, Ls = 256, E = 512, H = 8;
static constexpr int BL = Bb * Ls;  // 512

// workspace layout in floats
static constexpr size_t WS_QP = 0;
static constexpr size_t WS_KP = WS_QP + (size_t)BL * E;       // 262144
static constexpr size_t WS_VP = WS_KP + (size_t)BL * E;
static constexpr size_t WS_M  = WS_VP + (size_t)BL * E;       // BL*H*E = 2097152
static constexpr size_t WS_C  = WS_M  + (size_t)BL * H * E;   // 4096, layout [b][h][k]
static constexpr size_t WS_O  = WS_C  + (size_t)BL * H;       // 262144
static constexpr size_t WS_QK = WS_O  + (size_t)BL * E;       // B*H*L*L = 1048576
// total ~4.2M floats = 17 MB (ws is 1 GiB; poison cost is harness-fixed)

DEV_INLINE float dot4n(nfloat4 a, float4 b) {
  return a.x * b.x + a.y * b.y + a.z * b.z + a.w * b.w;
}

// ---------------- generic tiled fp32 GEMM core ----------------
// Tile is (16*RPT) rows x 64 cols, 256 threads, RPT outputs-rows/thread.
// Register double-buffered staging: next k-step's global loads are issued
// right after the first barrier so their latency hides under the FMA block —
// critical for the ~1-block/CU launches (K1/K6) where no other wavefronts
// cover the barrier-exposed load latency.
// NOTE (R3 post-mortem): K4 variants with M staged in LDS (8 waves/SIMD) and
// K5 with 4 rows/block were NEUTRAL-to-negative — K4 sits on its 43 us HBM
// floor with latency already hidden at ~5 waves/SIMD; reverted to the
// register-cached form (best measured: 437.6 us).
template <int TRANSB, int RPT>
DEV_INLINE void gemm_tile(const float* __restrict__ A, int lda,
                          const float* __restrict__ B, int ldb,
                          float* __restrict__ C, int ldc, int Ksz,
                          const float* __restrict__ bias, int i0, int j0) {
  constexpr int TM = 16 * RPT;
  __shared__ float As[16][TM + 4];
  __shared__ float Bs[16][68];
  const int t = threadIdx.x;
  const int tx = t & 15, ty = t >> 4;
  const int ar = t >> 2, ac = t & 3;  // staging: row 0..TM-1, k-chunk 0..3
  const bool aload = (t < 64 * RPT);
  float acc[RPT][4] = {};

  float4 av, bv;
  if (aload) av = *(const float4*)&A[(size_t)(i0 + ar) * lda + 4 * ac];
  if (TRANSB == 0)
    bv = *(const float4*)&B[(size_t)ty * ldb + (j0 + 4 * tx)];
  else
    bv = *(const float4*)&B[(size_t)(j0 + ar) * ldb + 4 * ac];

  for (int k0 = 0; k0 < Ksz; k0 += 16) {
    if (aload) {
      As[4 * ac + 0][ar] = av.x;
      As[4 * ac + 1][ar] = av.y;
      As[4 * ac + 2][ar] = av.z;
      As[4 * ac + 3][ar] = av.w;
    }
    if (TRANSB == 0) {
      *(float4*)&Bs[ty][4 * tx] = bv;
    } else {
      Bs[4 * ac + 0][ar] = bv.x;
      Bs[4 * ac + 1][ar] = bv.y;
      Bs[4 * ac + 2][ar] = bv.z;
      Bs[4 * ac + 3][ar] = bv.w;
    }
    __syncthreads();
    const int k1 = k0 + 16;
    if (k1 < Ksz) {  // prefetch next tile into registers during compute
      if (aload) av = *(const float4*)&A[(size_t)(i0 + ar) * lda + (k1 + 4 * ac)];
      if (TRANSB == 0)
        bv = *(const float4*)&B[(size_t)(k1 + ty) * ldb + (j0 + 4 * tx)];
      else
        bv = *(const float4*)&B[(size_t)(j0 + ar) * ldb + (k1 + 4 * ac)];
    }
#pragma unroll
    for (int kk = 0; kk < 16; ++kk) {
      float a[RPT];
      if constexpr (RPT == 4) {
        float4 a4 = *(const float4*)&As[kk][ty * 4];
        a[0] = a4.x; a[1] = a4.y; a[2] = a4.z; a[3] = a4.w;
      } else if constexpr (RPT == 2) {
        float2 a2 = *(const float2*)&As[kk][ty * 2];
        a[0] = a2.x; a[1] = a2.y;
      } else {
        a[0] = As[kk][ty];
      }
      float4 b4 = *(const float4*)&Bs[kk][tx * 4];
#pragma unroll
      for (int r = 0; r < RPT; ++r) {
        acc[r][0] += a[r] * b4.x;
        acc[r][1] += a[r] * b4.y;
        acc[r][2] += a[r] * b4.z;
        acc[r][3] += a[r] * b4.w;
      }
    }
    __syncthreads();
  }
#pragma unroll
  for (int r = 0; r < RPT; ++r) {
#pragma unroll
    for (int c2 = 0; c2 < 4; ++c2) {
      float v = acc[r][c2];
      if (bias) v += bias[j0 + tx * 4 + c2];
      C[(size_t)(i0 + ty * RPT + r) * ldc + (j0 + tx * 4 + c2)] = v;
    }
  }
}

// K1: qp = query@Wq, kp = key@Wk, vp = value@Wq  (bug preserved: vp uses Wq)
// 32-row tiles -> 384 blocks (1.5/CU): all CUs busy, cross-block latency cover.
__global__ __launch_bounds__(256) void k1_proj(
    const float* __restrict__ q, const float* __restrict__ k,
    const float* __restrict__ v, const float* __restrict__ Wq,
    const float* __restrict__ Wk, float* __restrict__ qp,
    float* __restrict__ kp, float* __restrict__ vp) {
  const float* A; const float* Bm; float* C;
  switch (blockIdx.z) {
    case 0:  A = q; Bm = Wq; C = qp; break;
    case 1:  A = k; Bm = Wk; C = kp; break;
    default: A = v; Bm = Wq; C = vp; break;
  }
  gemm_tile<0, 2>(A, 512, Bm, 512, C, 512, 512, nullptr,
                  blockIdx.y * 32, blockIdx.x * 64);
}

// K23 (merged): blocks 0..511 compute M[bk,h,e] = kp_h @ Wr_h (plus c[b,h,k]
// on the x==0 stripe); blocks 512..767 compute qk[b,h,q,k] = qp_h . kp_h.
// Both depend only on K1 (c is folded in K4) -> one launch, full concurrency.
__global__ __launch_bounds__(256) void k23(
    const float* __restrict__ kp, const float* __restrict__ Wr,
    const float* __restrict__ br, const float* __restrict__ qp,
    float* __restrict__ M, float* __restrict__ c, float* __restrict__ qk) {
  const int blk = blockIdx.x;
  if (blk < 512) {
    const int h = blk >> 6, rem = blk & 63;
    const int by = rem >> 3, bx = rem & 7;
    if (bx == 0 && threadIdx.x < 64) {
      const int row = by * 64 + threadIdx.x;  // bk in 0..511
      float s = 0.f;
      const float* kr = kp + (size_t)row * 512 + h * 64;
      const float* bb = br + h * 64;
#pragma unroll 8
      for (int d = 0; d < 64; ++d) s += bb[d] * kr[d];
      c[((size_t)(row >> 8) * 8 + h) * 256 + (row & 255)] = s;
    }
    gemm_tile<0, 4>(kp + h * 64, 512, Wr + (size_t)h * 64 * 512, 512,
                    M + (size_t)h * 512, 4096, 64, nullptr, by * 64, bx * 64);
  } else {
    const int idx = blk - 512;
    const int z = idx >> 4;                    // b*8 + h
    const int by = (idx >> 2) & 3, bx = idx & 3;
    const int b = z >> 3, h = z & 7;
    gemm_tile<1, 4>(qp + (size_t)b * 256 * 512 + h * 64, 512,
                    kp + (size_t)b * 256 * 512 + h * 64, 512,
                    qk + (size_t)z * 65536, 256, 64, nullptr, by * 64, bx * 64);
  }
}

// K4 (hot): for block (b,k,qquarter):
//   logits[b,q,k,h] = sum_e rel[b,q,k,e]*M[b,k,h,e] + qk[b,h,q,k] + c[b,h,k]
// Lane L owns e-slices [4L,4L+4) and [256+4L,4L+260): rel loads fully
// coalesced (1 KB per NT dwordx4). M cached per-lane (64 VGPR). Per-head
// partials reduced with a reduce-scatter butterfly; writer lanes fold in the
// precomputed qk scalar + loop-invariant c. rel software-pipelined one q-row
// ahead. Measured: at ~5 waves/SIMD this sits on the 43 us rel-stream HBM
// floor (LDS-staged M / 8-wave variant was neutral-to-negative, R3).
__global__ __launch_bounds__(256) void k4_rel(
    const float* __restrict__ rel, const float* __restrict__ Mw,
    const float* __restrict__ qk, const float* __restrict__ cbias,
    float* __restrict__ logits) {
  const int blk = blockIdx.x;       // 2048
  const int bk = blk >> 2;          // 0..511
  const int qq = blk & 3;
  const int b = bk >> 8, k = bk & 255;
  const int t = threadIdx.x, w = t >> 6, lane = t & 63;

  const float* Mbase = Mw + (size_t)bk * 8 * 512;
  float4 m0[8], m1[8];
#pragma unroll
  for (int h = 0; h < 8; ++h) {
    m0[h] = *(const float4*)(Mbase + h * 512 + 4 * lane);
    m1[h] = *(const float4*)(Mbase + h * 512 + 256 + 4 * lane);
  }

  // writer lane h mapping (bit-reversed 3-bit)
  const int hw = ((lane & 1) << 2) | (lane & 2) | ((lane >> 2) & 1);
  const bool writer = (lane < 8);
  const float cv = writer ? cbias[((size_t)b * 8 + hw) * 256 + k] : 0.f;

  const int q0 = qq * 64 + w;  // this wave's first q; step 4, 16 iters
  const nfloat4* relp =
      (const nfloat4*)(rel) + (((size_t)b * 256 + q0) * 256 + k) * 128;
  const float* qkp = qk + ((size_t)(b * 8 + hw) * 256 + q0) * 256 + k;
  float* lp = logits + (((size_t)b * 256 + q0) * 256 + k) * 8 + hw;
  const size_t REL_STRIDE = (size_t)4 * 256 * 128;  // q += 4, in float4s
  const size_t QK_STRIDE = (size_t)4 * 256;
  const size_t L_STRIDE = (size_t)4 * 256 * 8;

  const bool b0 = (lane & 1) != 0;
  const bool b1 = (lane & 2) != 0;
  const bool b2 = (lane & 4) != 0;

  nfloat4 r0 = __builtin_nontemporal_load(&relp[lane]);
  nfloat4 r1 = __builtin_nontemporal_load(&relp[64 + lane]);

  for (int i = 0; i < 16; ++i) {
    float qkv = 0.f;
    if (writer) qkv = *qkp;  // L2-hot scalar, issued early

    const bool more = (i < 15);
    nfloat4 nr0, nr1;
    if (more) {  // prefetch next q-row while computing current
      relp += REL_STRIDE;
      nr0 = __builtin_nontemporal_load(&relp[lane]);
      nr1 = __builtin_nontemporal_load(&relp[64 + lane]);
    }

    float acc[8];
#pragma unroll
    for (int h = 0; h < 8; ++h)
      acc[h] = dot4n(r0, m0[h]) + dot4n(r1, m1[h]);

    // reduce-scatter butterfly: bit0 picks h-bit2, bit1 -> h-bit1, bit2 -> h-bit0
    float s[4];
#pragma unroll
    for (int j = 0; j < 4; ++j) {
      float lo = acc[j], hi = acc[j + 4];
      float send = b0 ? lo : hi;
      float keep = b0 ? hi : lo;
      s[j] = keep + __shfl_xor(send, 1);
    }
    float u[2];
#pragma unroll
    for (int j = 0; j < 2; ++j) {
      float lo = s[j], hi = s[j + 2];
      float send = b1 ? lo : hi;
      float keep = b1 ? hi : lo;
      u[j] = keep + __shfl_xor(send, 2);
    }
    {
      float lo = u[0], hi = u[1];
      float send = b2 ? lo : hi;
      float keep = b2 ? hi : lo;
      float v = keep + __shfl_xor(send, 4);
      v += __shfl_xor(v, 8);
      v += __shfl_xor(v, 16);
      v += __shfl_xor(v, 32);
      if (writer) *lp = v + qkv + cv;
    }
    if (more) { r0 = nr0; r1 = nr1; }
    qkp += QK_STRIDE;
    lp += L_STRIDE;
  }
}

// K5: softmax over k per (b,q,h); writes normalized a in place (d_out region),
// then o[b,q,:] = sum_k a[k,h] * vp[b,k,:].
// Two q-rows per block: each vp float4 is loaded once and used for both rows
// -> halves the vp L2 traffic. (4-row variant measured neutral, R3.)
__global__ __launch_bounds__(256) void k5_softmax(float* __restrict__ logits,
                                                  const float* __restrict__ vp,
                                                  float* __restrict__ o) {
  const int pr = blockIdx.x;     // 0..255
  const int bq0 = pr * 2;
  const int b = bq0 >> 8;        // both rows in same batch (256 rows/batch)
  const int t = threadIdx.x;
  const float SCALE = 0.125f;    // 1/sqrt(64)

  __shared__ float tr[2][8][272];  // [row][h][k], stride 272 -> conflict-free
  __shared__ float mx[2][8], sm[2][8];
  __shared__ float ob[2][512];     // split-k partial combine

  float x[2][8];
#pragma unroll
  for (int r = 0; r < 2; ++r) {
    float* L = logits + (size_t)(bq0 + r) * 2048;
    float4 x0 = ((float4*)L)[t * 2];
    float4 x1 = ((float4*)L)[t * 2 + 1];
    x[r][0] = x0.x; x[r][1] = x0.y; x[r][2] = x0.z; x[r][3] = x0.w;
    x[r][4] = x1.x; x[r][5] = x1.y; x[r][6] = x1.z; x[r][7] = x1.w;
#pragma unroll
    for (int j = 0; j < 8; ++j) x[r][j] *= SCALE;
#pragma unroll
    for (int hh = 0; hh < 8; ++hh) tr[r][hh][t] = x[r][hh];
  }
  __syncthreads();
  const int g = t >> 5, j = t & 31;
#pragma unroll
  for (int r = 0; r < 2; ++r) {
    float m = -1e30f;
#pragma unroll
    for (int i = 0; i < 8; ++i) m = fmaxf(m, tr[r][g][j + 32 * i]);
#pragma unroll
    for (int off = 16; off >= 1; off >>= 1) m = fmaxf(m, __shfl_down(m, off, 32));
    if (j == 0) mx[r][g] = m;
  }
  __syncthreads();
  float p[2][8];
#pragma unroll
  for (int r = 0; r < 2; ++r)
#pragma unroll
    for (int hh = 0; hh < 8; ++hh) p[r][hh] = __expf(x[r][hh] - mx[r][hh]);
#pragma unroll
  for (int r = 0; r < 2; ++r)
#pragma unroll
    for (int hh = 0; hh < 8; ++hh) tr[r][hh][t] = p[r][hh];
  __syncthreads();
#pragma unroll
  for (int r = 0; r < 2; ++r) {
    float ss = 0.f;
#pragma unroll
    for (int i = 0; i < 8; ++i) ss += tr[r][g][j + 32 * i];
#pragma unroll
    for (int off = 16; off >= 1; off >>= 1) ss += __shfl_down(ss, off, 32);
    if (j == 0) sm[r][g] = ss;
  }
  __syncthreads();
#pragma unroll
  for (int r = 0; r < 2; ++r) {
    float inv[8];
#pragma unroll
    for (int hh = 0; hh < 8; ++hh) inv[hh] = 1.0f / sm[r][hh];
    float* L = logits + (size_t)(bq0 + r) * 2048;
    ((float4*)L)[t * 2] = make_float4(p[r][0] * inv[0], p[r][1] * inv[1],
                                      p[r][2] * inv[2], p[r][3] * inv[3]);
    ((float4*)L)[t * 2 + 1] = make_float4(p[r][4] * inv[4], p[r][5] * inv[5],
                                          p[r][6] * inv[6], p[r][7] * inv[7]);
  }

  // o accumulation: threads split into two k-halves; each handles 4 cols via
  // float4 loads (16 B/lane) shared across both q-rows; LDS partial combine.
  const int g2 = t >> 7, tc = t & 127;  // k-half, col-group (cols 4tc..4tc+3)
  const int hc = tc >> 4;               // head of this col group
  const float4* V4 =
      (const float4*)(vp + (size_t)b * 256 * 512 + (size_t)g2 * 128 * 512) + tc;
  const float* t0 = &tr[0][hc][g2 * 128];
  const float* t1 = &tr[1][hc][g2 * 128];
  float a0x = 0.f, a0y = 0.f, a0z = 0.f, a0w = 0.f;
  float a1x = 0.f, a1y = 0.f, a1z = 0.f, a1w = 0.f;
#pragma unroll 8
  for (int kk = 0; kk < 128; ++kk) {
    float4 vv = V4[(size_t)kk * 128];
    const float w0 = t0[kk], w1 = t1[kk];  // unnormalized p
    a0x += w0 * vv.x; a0y += w0 * vv.y; a0z += w0 * vv.z; a0w += w0 * vv.w;
    a1x += w1 * vv.x; a1y += w1 * vv.y; a1z += w1 * vv.z; a1w += w1 * vv.w;
  }
  if (g2) {
    ob[0][4 * tc + 0] = a0x; ob[0][4 * tc + 1] = a0y;
    ob[0][4 * tc + 2] = a0z; ob[0][4 * tc + 3] = a0w;
    ob[1][4 * tc + 0] = a1x; ob[1][4 * tc + 1] = a1y;
    ob[1][4 * tc + 2] = a1z; ob[1][4 * tc + 3] = a1w;
  }
  __syncthreads();
  if (!g2) {
    const float i0 = 1.0f / sm[0][hc], i1 = 1.0f / sm[1][hc];
    a0x = (a0x + ob[0][4 * tc + 0]) * i0;
    a0y = (a0y + ob[0][4 * tc + 1]) * i0;
    a0z = (a0z + ob[0][4 * tc + 2]) * i0;
    a0w = (a0w + ob[0][4 * tc + 3]) * i0;
    a1x = (a1x + ob[1][4 * tc + 0]) * i1;
    a1y = (a1y + ob[1][4 * tc + 1]) * i1;
    a1z = (a1z + ob[1][4 * tc + 2]) * i1;
    a1w = (a1w + ob[1][4 * tc + 3]) * i1;
    ((float4*)(o + (size_t)bq0 * 512))[tc] = make_float4(a0x, a0y, a0z, a0w);
    ((float4*)(o + (size_t)(bq0 + 1) * 512))[tc] = make_float4(a1x, a1y, a1z, a1w);
  }
}

// K6: out = o @ Wo.T + bo.  16-row tiles -> 256 blocks: all CUs busy
// (was 64 blocks = 1/4 of the chip).
__global__ __launch_bounds__(256) void k6_out(const float* __restrict__ o,
                                              const float* __restrict__ Wo,
                                              const float* __restrict__ bo,
                                              float* __restrict__ out) {
  gemm_tile<1, 1>(o, 512, Wo, 512, out, 512, 512, bo,
                  blockIdx.y * 16, blockIdx.x * 64);
}

extern "C" void kernel_launch(void* const* d_in, const int* in_sizes, int n_in,
                              void* d_out, int out_size, void* d_ws,
                              size_t ws_size, hipStream_t stream) {
  const float* query = (const float*)d_in[0];
  const float* key   = (const float*)d_in[1];
  const float* value = (const float*)d_in[2];
  const float* rel   = (const float*)d_in[3];
  const float* Wq    = (const float*)d_in[4];
  const float* Wk    = (const float*)d_in[5];
  // d_in[6] = Wv: unused (reference bug: v = value @ Wq)
  const float* Wr    = (const float*)d_in[7];
  const float* br    = (const float*)d_in[8];
  const float* Wo    = (const float*)d_in[9];
  const float* bo    = (const float*)d_in[10];

  float* out = (float*)d_out;                   // (B,L,E) = 262144 floats
  float* a   = (float*)d_out + (size_t)BL * E;  // (B,L,L,H); also logits scratch

  float* ws = (float*)d_ws;
  float* qp  = ws + WS_QP;
  float* kp  = ws + WS_KP;
  float* vp  = ws + WS_VP;
  float* M   = ws + WS_M;
  float* c   = ws + WS_C;
  float* o   = ws + WS_O;
  float* qkb = ws + WS_QK;

  // K1: projections (3 GEMMs 512x512x512), 32-row tiles
  k1_proj<<<dim3(8, 16, 3), 256, 0, stream>>>(query, key, value, Wq, Wk, qp, kp, vp);
  // K23: M per head + c bias (blocks 0..511) and qk GEMMs (blocks 512..767)
  k23<<<dim3(768), 256, 0, stream>>>(kp, Wr, br, qp, M, c, qkb);
  // K4: logits = rel.M + qk + c  (2048 blocks, rel software-pipelined)
  k4_rel<<<dim3(2048), 256, 0, stream>>>(rel, M, qkb, c, a);
  // K5: softmax (in-place -> a) + o = a.vp  (2 q-rows per block)
  k5_softmax<<<dim3(256), 256, 0, stream>>>(a, vp, o);
  // K6: out = o @ Wo.T + bo  (16-row tiles, 256 blocks)
  k6_out<<<dim3(8, 32, 1), 256, 0, stream>>>(o, Wo, bo, out);
}